// Round 19
// baseline (228.392 us; speedup 1.0000x reference)
//
#include <hip/hip_runtime.h>
#include <hip/hip_fp16.h>
#include <math.h>

#define B_EV    16
#define N_NODES 2048
#define K_NN    16
#define F_IN    64
#define L_OUT   64
#define NT      (B_EV * N_NODES)      // 32768
#define EDGES   (NT * K_NN)           // 524288

typedef __attribute__((ext_vector_type(8)))  short bh8;    // 8 bf16 = 4 VGPR
typedef __attribute__((ext_vector_type(16))) float f32x16; // MFMA acc
typedef __attribute__((ext_vector_type(8)))  unsigned short us8;

__device__ inline unsigned short bf16_rne(float f) {
  unsigned int u = __float_as_uint(f);
  return (unsigned short)((u + 0x7FFFu + ((u >> 16) & 1u)) >> 16);
}
__device__ inline float bf16f(unsigned short h) {
  return __uint_as_float(((unsigned int)h) << 16);
}

// async global->LDS, 16B per lane; LDS dest must be wave-uniform base + lane*16
__device__ inline void gload16(const void* g, void* l) {
  __builtin_amdgcn_global_load_lds(
      (const __attribute__((address_space(1))) void*)(g),
      (__attribute__((address_space(3))) void*)(l), 16, 0, 0);
}

// exact numpy-fp32-emulated score -> monotone sortable 64-bit key (s32, idx)
__device__ inline unsigned long long score_key(const float* xiW,
                                               const float* __restrict__ xev,
                                               int mcol, float sqn,
                                               const float* __restrict__ sqev) {
  const float4* xm = (const float4*)(xev + (size_t)mcol * F_IN);
  double d0 = 0.0, d1 = 0.0, d2 = 0.0, d3 = 0.0;
  #pragma unroll
  for (int fq = 0; fq < 16; fq += 4) {
    float4 c0 = xm[fq + 0], c1 = xm[fq + 1], c2 = xm[fq + 2], c3 = xm[fq + 3];
    float4 x0 = *(const float4*)(xiW + fq * 4);
    float4 x1 = *(const float4*)(xiW + fq * 4 + 4);
    float4 x2 = *(const float4*)(xiW + fq * 4 + 8);
    float4 x3 = *(const float4*)(xiW + fq * 4 + 12);
    d0 = fma((double)x0.x, (double)c0.x, d0);
    d0 = fma((double)x0.y, (double)c0.y, d0);
    d0 = fma((double)x0.z, (double)c0.z, d0);
    d0 = fma((double)x0.w, (double)c0.w, d0);
    d1 = fma((double)x1.x, (double)c1.x, d1);
    d1 = fma((double)x1.y, (double)c1.y, d1);
    d1 = fma((double)x1.z, (double)c1.z, d1);
    d1 = fma((double)x1.w, (double)c1.w, d1);
    d2 = fma((double)x2.x, (double)c2.x, d2);
    d2 = fma((double)x2.y, (double)c2.y, d2);
    d2 = fma((double)x2.z, (double)c2.z, d2);
    d2 = fma((double)x2.w, (double)c2.w, d2);
    d3 = fma((double)x3.x, (double)c3.x, d3);
    d3 = fma((double)x3.y, (double)c3.y, d3);
    d3 = fma((double)x3.z, (double)c3.z, d3);
    d3 = fma((double)x3.w, (double)c3.w, d3);
  }
  float dot32 = (float)((d0 + d1) + (d2 + d3));
  float sv = __fsub_rn(__fadd_rn(sqn, sqev[mcol]), __fmul_rn(2.0f, dot32));
  unsigned int fb = __float_as_uint(sv);
  fb = (fb & 0x80000000u) ? ~fb : (fb | 0x80000000u);
  return ((unsigned long long)fb << 32) | (unsigned int)mcol;
}

// ---------------- K1: u = x@(W1-W2), v = x@W2  (+fused sq & bf16 hi/lo split) ----
__global__ __launch_bounds__(256) void k_uv(const float* __restrict__ x,
                                            const float* __restrict__ W,
                                            float* __restrict__ u,
                                            float* __restrict__ v,
                                            float* __restrict__ sq,
                                            unsigned short* __restrict__ xh,
                                            unsigned short* __restrict__ xl) {
  __shared__ float xs[64][64];   // 16 KB
  const int t = threadIdx.x;
  const int l = t & 63, g = t >> 6;
  const int nodeBase = blockIdx.x * 64;

  {
    const float4* gx = (const float4*)(x + (size_t)nodeBase * 64);
    float4* lx = (float4*)&xs[0][0];
    #pragma unroll
    for (int p = 0; p < 4; ++p) lx[p * 256 + t] = gx[p * 256 + t];
  }
  float wdc[64], w2c[64];
  #pragma unroll
  for (int f = 0; f < 64; ++f) {
    float w1v = W[f * 64 + l];
    float w2v = W[4096 + f * 64 + l];
    wdc[f] = w1v - w2v;
    w2c[f] = w2v;
  }
  __syncthreads();

  // fused sq: bit-exact numpy pairwise fp32 (8 lanes/node, shfl tree)
  #pragma unroll
  for (int p = 0; p < 2; ++p) {
    int n = p * 32 + (t >> 3), j = t & 7;
    float xv = xs[n][j];
    float s = __fmul_rn(xv, xv);
    #pragma unroll
    for (int i = 1; i < 8; ++i) {
      float c = xs[n][j + 8 * i];
      s = __fadd_rn(s, __fmul_rn(c, c));
    }
    s = __fadd_rn(s, __shfl_xor(s, 1));
    s = __fadd_rn(s, __shfl_xor(s, 2));
    s = __fadd_rn(s, __shfl_xor(s, 4));
    if (j == 0) sq[nodeBase + n] = s;
  }
  // fused cvt: 4 float4 per thread
  #pragma unroll
  for (int p = 0; p < 4; ++p) {
    int i = p * 256 + t;
    float4 vv = ((const float4*)&xs[0][0])[i];
    ushort4 h, lo;
    h.x = bf16_rne(vv.x); lo.x = bf16_rne(vv.x - bf16f(h.x));
    h.y = bf16_rne(vv.y); lo.y = bf16_rne(vv.y - bf16f(h.y));
    h.z = bf16_rne(vv.z); lo.z = bf16_rne(vv.z - bf16f(h.z));
    h.w = bf16_rne(vv.w); lo.w = bf16_rne(vv.w - bf16f(h.w));
    ((ushort4*)xh)[(size_t)nodeBase * 16 + i] = h;
    ((ushort4*)xl)[(size_t)nodeBase * 16 + i] = lo;
  }

  for (int rep = 0; rep < 16; ++rep) {
    int n = rep * 4 + g;
    const float4* xr = (const float4*)xs[n];
    float au = 0.f, av = 0.f;
    #pragma unroll
    for (int fq = 0; fq < 16; ++fq) {
      float4 xv = xr[fq];
      au = fmaf(xv.x, wdc[fq * 4 + 0], au); av = fmaf(xv.x, w2c[fq * 4 + 0], av);
      au = fmaf(xv.y, wdc[fq * 4 + 1], au); av = fmaf(xv.y, w2c[fq * 4 + 1], av);
      au = fmaf(xv.z, wdc[fq * 4 + 2], au); av = fmaf(xv.z, w2c[fq * 4 + 2], av);
      au = fmaf(xv.w, wdc[fq * 4 + 3], au); av = fmaf(xv.w, w2c[fq * 4 + 3], av);
    }
    u[(size_t)(nodeBase + n) * 64 + l] = au;
    v[(size_t)(nodeBase + n) * 64 + l] = av;
  }
}

// ---------------- K2a: strip GEMM -> S (fp16 screening, 2-pass MFMA, column-halved) ----------------
__global__ __launch_bounds__(256, 6) void k_gemm(const unsigned short* __restrict__ xh,
                                                 const unsigned short* __restrict__ xl,
                                                 const float* __restrict__ sq,
                                                 unsigned short* __restrict__ Sbuf,
                                                 int evBase) {
  __shared__ char xb[16384];                              // B-hi tile, swizzled
  __shared__ __align__(16) unsigned short Sh[32 * 128];   // fp16 S stage; prologue: A staging (8KB)
  const int t    = threadIdx.x;
  const int w    = t >> 6;
  const int lane = t & 63;
  const int ev    = evBase + (blockIdx.x >> 7);
  const int rem   = blockIdx.x & 127;
  const int strip = rem >> 1;
  const int half  = rem & 1;
  const int rowBase = strip * 32;
  const int T0 = half * 8;
  const size_t evNode = (size_t)ev * N_NODES;
  const float* __restrict__ sqev = sq + evNode;
  unsigned short* __restrict__ Sev =
      Sbuf + (size_t)(ev - evBase) * N_NODES * N_NODES;
  char* Sc = (char*)Sh;

  {
    int col = t >> 3;
    int fbs = ((t & 7) << 4) ^ ((col & 7) << 4);
    gload16((const char*)(xh + (evNode + rowBase + col) * 64) + fbs, Sc + t * 16);
    gload16((const char*)(xl + (evNode + rowBase + col) * 64) + fbs, Sc + 4096 + t * 16);
    #pragma unroll
    for (int p = 0; p < 4; ++p) {
      const int colB = p * 32 + (t >> 3);
      const char* g = (const char*)(xh + (evNode + T0 * 128 + colB) * 64) + fbs;
      gload16(g, xb + p * 4096 + t * 16);
    }
  }
  __syncthreads();
  bh8 ah[4], al[4];
  {
    int row = lane & 31;
    int fb  = (lane >> 5) * 16;
    #pragma unroll
    for (int ks = 0; ks < 4; ++ks) {
      int off = (row * 128 + ks * 32 + fb) ^ ((row & 7) << 4);
      ah[ks] = *(const bh8*)(Sc + off);
      al[ks] = *(const bh8*)(Sc + 4096 + off);
    }
  }
  __syncthreads();

  for (int T = T0; T < T0 + 8; ++T) {
    const int tileCol = T * 128;
    {
      f32x16 acc;
      #pragma unroll
      for (int q = 0; q < 16; ++q) acc[q] = 0.f;
      int colIn = w * 32 + (lane & 31);
      int fb = (lane >> 5) * 16;
      #pragma unroll
      for (int ks = 0; ks < 4; ++ks) {
        int off = (colIn * 128 + ks * 32 + fb) ^ ((colIn & 7) << 4);
        bh8 bh = *(const bh8*)(xb + off);
        acc = __builtin_amdgcn_mfma_f32_32x32x16_bf16(ah[ks], bh, acc, 0, 0, 0);
        acc = __builtin_amdgcn_mfma_f32_32x32x16_bf16(al[ks], bh, acc, 0, 0, 0);
      }
      float sqc = sqev[tileCol + colIn];
      #pragma unroll
      for (int reg = 0; reg < 16; ++reg) {
        int m = (reg & 3) + 8 * (reg >> 2) + 4 * (lane >> 5);
        Sh[m * 128 + colIn] =
            __half_as_ushort(__float2half(fmaf(-2.0f, acc[reg], sqc)));
      }
    }
    __syncthreads();
    if (T < T0 + 7) {
      #pragma unroll
      for (int p = 0; p < 4; ++p) {
        const int colB = p * 32 + (t >> 3);
        const int fbs = ((t & 7) << 4) ^ (((t >> 3) & 7) << 4);
        const char* g = (const char*)(xh + (evNode + tileCol + 128 + colB) * 64) + fbs;
        gload16(g, xb + p * 4096 + t * 16);
      }
    }
    {
      int r  = t >> 3;
      int cg = t & 7;
      unsigned short* gS =
          Sev + (size_t)(rowBase + r) * N_NODES + tileCol + cg * 16;
      const uint4* lS = (const uint4*)(Sh + r * 128 + cg * 16);
      *(uint4*)gS = lS[0];
      *(uint4*)(gS + 8) = lS[1];
    }
    __syncthreads();
  }
}

// ---------------- K2b: fused screen+rescore+rank (single row/wave; cheap threshold) ----------------
// thr = max over 16 four-lane-group mins + delta (>= exact-16th + delta; superset
// holds for delta >= 2*screen-error). thr rank ~ coupon-collector over 16 groups:
// E~54, P(rank>434) ~ 1e-11 -> SCR_CAP=448 makes overflow negligible (r18 failure
// was CAP=192 overflow at P~1e-4/row).
#define SCR_CAP 448
#define SEL_DELTA 1.0f

__global__ __launch_bounds__(256, 1) void k_sel(const float* __restrict__ x,
                                                const float* __restrict__ sq,
                                                const unsigned short* __restrict__ Sbuf,
                                                int* __restrict__ nidx,
                                                int rowBase) {
  __shared__ float xiS[4][64];
  __shared__ int candLDS[4][SCR_CAP];
  __shared__ unsigned long long keysLDS[4][SCR_CAP];
  const int w = threadIdx.x >> 6, lane = threadIdx.x & 63;
  const int rowInChunk = blockIdx.x * 4 + w;
  const int grow = rowBase + rowInChunk;
  const int ev = grow >> 11;
  const int rowInEv = grow & 2047;
  const size_t evNode = (size_t)ev * N_NODES;
  const unsigned short* __restrict__ Srow = Sbuf + (size_t)rowInChunk * N_NODES;
  const float* __restrict__ sqev = sq + evNode;
  const float* __restrict__ xev = x + evNode * F_IN;

  xiS[w][lane] = x[(evNode + rowInEv) * F_IN + lane];   // per-wave slice

  // ---- screening loads + lane-min ----
  us8 pk[4];
  #pragma unroll
  for (int q = 0; q < 4; ++q)
    pk[q] = *(const us8*)(Srow + q * 512 + lane * 8);

  float mn = 3.4e38f;
  #pragma unroll
  for (int q = 0; q < 4; ++q) {
    #pragma unroll
    for (int e = 0; e < 8; ++e)
      mn = fminf(mn, __half2float(__ushort_as_half(pk[q][e])));
  }
  // group-of-4 min, then max across the 16 groups (6 shfl stages total)
  mn = fminf(mn, __shfl_xor(mn, 1));
  mn = fminf(mn, __shfl_xor(mn, 2));
  mn = fmaxf(mn, __shfl_xor(mn, 4));
  mn = fmaxf(mn, __shfl_xor(mn, 8));
  mn = fmaxf(mn, __shfl_xor(mn, 16));
  mn = fmaxf(mn, __shfl_xor(mn, 32));
  const float thr = mn + SEL_DELTA;

  // ---- masks + prefix scan + compact into LDS ----
  unsigned int msk[4];
  int c = 0;
  #pragma unroll
  for (int q = 0; q < 4; ++q) {
    unsigned int m = 0;
    #pragma unroll
    for (int e = 0; e < 8; ++e) {
      float v = __half2float(__ushort_as_half(pk[q][e]));
      m |= (v <= thr) ? (1u << e) : 0u;
    }
    msk[q] = m;
    c += __popc(m);
  }
  int incl = c;
  #pragma unroll
  for (int off = 1; off < 64; off <<= 1) {
    int n = __shfl_up(incl, off);
    if (lane >= off) incl += n;
  }
  int pos = incl - c;
  int total = __shfl(incl, 63);
  const int cn = (total < SCR_CAP) ? total : SCR_CAP;
  #pragma unroll
  for (int q = 0; q < 4; ++q) {
    unsigned int m = msk[q];
    while (m) {
      int e = __ffs(m) - 1;
      m &= m - 1;
      if (pos < SCR_CAP) candLDS[w][pos] = q * 512 + lane * 8 + e;
      ++pos;
    }
  }

  // ---- exact rescore (numpy-fp32-emulated; fp64 dot), 64 candidates/pass ----
  const float sqn = sqev[rowInEv];
  const float* xiW = xiS[w];
  for (int bs = 0; bs < cn; bs += 64) {
    int ci = bs + lane;
    bool act = ci < cn;
    int mcol = act ? candLDS[w][ci] : 0;
    unsigned long long key = score_key(xiW, xev, mcol, sqn, sqev);
    if (act) keysLDS[w][ci] = key;
  }

  // ---- rank via broadcast passes (keys unique; stable ties by idx) ----
  const size_t outBase = (evNode + rowInEv) * K_NN;
  for (int bs = 0; bs < cn; bs += 64) {
    int ci = bs + lane;
    bool act = ci < cn;
    unsigned long long kk = act ? keysLDS[w][ci] : ~0ull;
    int r = 0;
    for (int i = 0; i < cn; ++i)
      r += (keysLDS[w][i] < kk) ? 1 : 0;
    if (act && r < K_NN)
      nidx[outBase + r] = (int)evNode + (int)(kk & 0x7FFFFFFFu);
  }
}

// ---------------- K2-fallback: fused kNN (round-4 validated path) ----------------
#define NS 16
#define NC 128
union KnnSmem {
  struct {
    char  xb[32768];
    float S[32 * 129];
  } a;
  struct {
    float sc[32][NC + 1];
    int   id[32][NC + 1];
    int   cand[32][24];
    float resc[32][24];
  } b;
};

__global__ __launch_bounds__(256, 3) void k_knn(const float* __restrict__ x,
                                                const unsigned short* __restrict__ xh,
                                                const unsigned short* __restrict__ xl,
                                                const float* __restrict__ sq,
                                                int* __restrict__ nidx) {
  __shared__ KnnSmem sm;
  const int t    = threadIdx.x;
  const int r    = t & 31;
  const int c8   = t >> 5;
  const int w    = t >> 6;
  const int lane = t & 63;
  const int ev    = blockIdx.x >> 6;
  const int strip = blockIdx.x & 63;
  const int rowBase = strip * 32;
  const size_t evNode = (size_t)ev * N_NODES;
  const float* __restrict__ sqev = sq + evNode;

  {
    int col = t >> 3;
    int fb  = (t & 7) << 4;
    const char* gh = (const char*)(xh + (evNode + rowBase + col) * 64) + fb;
    const char* gl = (const char*)(xl + (evNode + rowBase + col) * 64) + fb;
    int off = (col * 128 + fb) ^ ((col & 7) << 4);
    *(uint4*)(sm.a.xb + off)         = *(const uint4*)gh;
    *(uint4*)(sm.a.xb + 16384 + off) = *(const uint4*)gl;
  }
  __syncthreads();
  bh8 ah[4], al[4];
  {
    int row = lane & 31;
    int fb  = (lane >> 5) * 16;
    #pragma unroll
    for (int ks = 0; ks < 4; ++ks) {
      int off = (row * 128 + ks * 32 + fb) ^ ((row & 7) << 4);
      ah[ks] = *(const bh8*)(sm.a.xb + off);
      al[ks] = *(const bh8*)(sm.a.xb + 16384 + off);
    }
  }

  float dist[NS]; int idxk[NS];
  #pragma unroll
  for (int q = 0; q < NS; ++q) { dist[q] = 3.4e38f; idxk[q] = 0x7FFFFFFF; }
  float curMax = 3.4e38f;

  for (int T = 0; T < 16; ++T) {
    __syncthreads();
    const int tileCol = T * 128;
    #pragma unroll
    for (int p = 0; p < 8; ++p) {
      int idx16 = (p & 3) * 256 + t;
      int col = idx16 >> 3;
      int fb  = (idx16 & 7) << 4;
      const unsigned short* src = (p < 4) ? xh : xl;
      const char* g = (const char*)(src + (evNode + tileCol + col) * 64) + fb;
      int off = ((p < 4) ? 0 : 16384) + ((col * 128 + fb) ^ ((col & 7) << 4));
      *(uint4*)(sm.a.xb + off) = *(const uint4*)g;
    }
    __syncthreads();
    {
      f32x16 acc;
      #pragma unroll
      for (int q = 0; q < 16; ++q) acc[q] = 0.f;
      int colIn = w * 32 + (lane & 31);
      int fb = (lane >> 5) * 16;
      #pragma unroll
      for (int ks = 0; ks < 4; ++ks) {
        int off = (colIn * 128 + ks * 32 + fb) ^ ((colIn & 7) << 4);
        bh8 bh = *(const bh8*)(sm.a.xb + off);
        bh8 bl = *(const bh8*)(sm.a.xb + 16384 + off);
        acc = __builtin_amdgcn_mfma_f32_32x32x16_bf16(ah[ks], bh, acc, 0, 0, 0);
        acc = __builtin_amdgcn_mfma_f32_32x32x16_bf16(ah[ks], bl, acc, 0, 0, 0);
        acc = __builtin_amdgcn_mfma_f32_32x32x16_bf16(al[ks], bh, acc, 0, 0, 0);
      }
      float sqc = sqev[tileCol + colIn];
      #pragma unroll
      for (int reg = 0; reg < 16; ++reg) {
        int m = (reg & 3) + 8 * (reg >> 2) + 4 * (lane >> 5);
        sm.a.S[m * 129 + colIn] = fmaf(-2.0f, acc[reg], sqc);
      }
    }
    __syncthreads();
    for (int j = 0; j < 16; ++j) {
      int cIn = c8 * 16 + j;
      float s = sm.a.S[r * 129 + cIn];
      if (s <= curMax) {
        int col = tileCol + cIn;
        float bv = dist[0]; int bi = idxk[0]; int slot = 0;
        #pragma unroll
        for (int q = 1; q < NS; ++q) {
          bool worse = (dist[q] > bv) || ((dist[q] == bv) && (idxk[q] > bi));
          slot = worse ? q : slot;
          bv = worse ? dist[q] : bv;
          bi = worse ? idxk[q] : bi;
        }
        if ((s < bv) || ((s == bv) && (col < bi))) {
          #pragma unroll
          for (int q = 0; q < NS; ++q) {
            dist[q] = (q == slot) ? s : dist[q];
            idxk[q] = (q == slot) ? col : idxk[q];
          }
          float cm = dist[0];
          #pragma unroll
          for (int q = 1; q < NS; ++q) cm = fmaxf(cm, dist[q]);
          curMax = cm;
        }
      }
    }
  }

  __syncthreads();
  #pragma unroll
  for (int q = 0; q < NS; ++q) {
    sm.b.sc[r][c8 * NS + q] = dist[q];
    sm.b.id[r][c8 * NS + q] = idxk[q];
  }
  __syncthreads();

  if (t < 32) {
    float dd[24]; int di[24];
    #pragma unroll
    for (int q = 0; q < 24; ++q) { dd[q] = 3.4e38f; di[q] = 0x7FFFFFFF; }
    for (int c = 0; c < NC; ++c) {
      float s = sm.b.sc[t][c];
      int m = sm.b.id[t][c];
      float bv = dd[0]; int bi = di[0]; int slot = 0;
      #pragma unroll
      for (int q = 1; q < 24; ++q) {
        bool worse = (dd[q] > bv) || ((dd[q] == bv) && (di[q] > bi));
        slot = worse ? q : slot;
        bv = worse ? dd[q] : bv;
        bi = worse ? di[q] : bi;
      }
      if ((s < bv) || ((s == bv) && (m < bi))) {
        #pragma unroll
        for (int q = 0; q < 24; ++q) {
          dd[q] = (q == slot) ? s : dd[q];
          di[q] = (q == slot) ? m : di[q];
        }
      }
    }
    #pragma unroll
    for (int q = 0; q < 24; ++q) sm.b.cand[t][q] = di[q];
  }
  __syncthreads();

  {
    float4 xi[16];
    const float4* xr = (const float4*)(x + (evNode + rowBase + r) * F_IN);
    #pragma unroll
    for (int fq = 0; fq < 16; ++fq) xi[fq] = xr[fq];
    const float sqn = sqev[rowBase + r];
    const float* __restrict__ xev = x + evNode * F_IN;
    #pragma unroll
    for (int ii = 0; ii < 3; ++ii) {
      int i = c8 + ii * 8;
      int m = sm.b.cand[r][i];
      const float4* xm = (const float4*)(xev + (size_t)m * F_IN);
      double dot = 0.0;
      #pragma unroll
      for (int fq = 0; fq < 16; ++fq) {
        float4 cc = xm[fq];
        dot = fma((double)xi[fq].x, (double)cc.x, dot);
        dot = fma((double)xi[fq].y, (double)cc.y, dot);
        dot = fma((double)xi[fq].z, (double)cc.z, dot);
        dot = fma((double)xi[fq].w, (double)cc.w, dot);
      }
      const float dot32 = (float)dot;
      sm.b.resc[r][i] = __fsub_rn(__fadd_rn(sqn, sqev[m]),
                                  __fmul_rn(2.0f, dot32));
    }
  }
  __syncthreads();

  if (t < 32) {
    float dd[K_NN]; int di[K_NN];
    #pragma unroll
    for (int q = 0; q < K_NN; ++q) { dd[q] = 3.4e38f; di[q] = 0x7FFFFFFF; }
    for (int c = 0; c < 24; ++c) {
      float s = sm.b.resc[t][c];
      int m = sm.b.cand[t][c];
      float bv = dd[0]; int bi = di[0]; int slot = 0;
      #pragma unroll
      for (int q = 1; q < K_NN; ++q) {
        bool worse = (dd[q] > bv) || ((dd[q] == bv) && (di[q] > bi));
        slot = worse ? q : slot;
        bv = worse ? dd[q] : bv;
        bi = worse ? di[q] : bi;
      }
      if ((s < bv) || ((s == bv) && (m < bi))) {
        #pragma unroll
        for (int q = 0; q < K_NN; ++q) {
          dd[q] = (q == slot) ? s : dd[q];
          di[q] = (q == slot) ? m : di[q];
        }
      }
    }
    const size_t row = evNode + rowBase + t;
    #pragma unroll
    for (int q = 0; q < K_NN; ++q)
      nidx[row * K_NN + q] = (int)evNode + di[q];
  }
}

// ---------------- K3: BN statistics over all edges ----------------
#define NB_ST 32
__global__ __launch_bounds__(256) void k_stats(const float* __restrict__ u,
                                               const float* __restrict__ v,
                                               const int* __restrict__ nidx,
                                               const float* __restrict__ bvec,
                                               float* __restrict__ stats) {
  __shared__ float red1[4][64];
  __shared__ float red2[4][64];
  const int l = threadIdx.x & 63, g = threadIdx.x >> 6;
  const int base = blockIdx.x * NB_ST;
  const float bl = bvec[l];
  float s1 = 0.f, s2 = 0.f;
  for (int nn = g; nn < NB_ST; nn += 4) {
    const int node = base + nn;
    const float ui = u[(size_t)node * 64 + l] + bl;
    const int* ip = nidx + (size_t)node * K_NN;
    int idx[16];
    #pragma unroll
    for (int q = 0; q < 4; ++q)
      *(int4*)&idx[q * 4] = *(const int4*)(ip + q * 4);
    #pragma unroll
    for (int k = 0; k < K_NN; ++k) {
      const float vj = v[(size_t)idx[k] * 64 + l];
      const float h = ui + vj;
      s1 += h;
      s2 = fmaf(h, h, s2);
    }
  }
  red1[g][l] = s1; red2[g][l] = s2;
  __syncthreads();
  if (g == 0) {
    float t1 = red1[0][l] + red1[1][l] + red1[2][l] + red1[3][l];
    float t2 = red2[0][l] + red2[1][l] + red2[2][l] + red2[3][l];
    atomicAdd(&stats[l], t1);
    atomicAdd(&stats[64 + l], t2);
  }
}

// ---------------- K4: normalize + relu + mean over K ----------------
__global__ __launch_bounds__(256) void k_out(const float* __restrict__ u,
                                             const float* __restrict__ v,
                                             const int* __restrict__ nidx,
                                             const float* __restrict__ bvec,
                                             const float* __restrict__ gamma,
                                             const float* __restrict__ beta,
                                             const float* __restrict__ stats,
                                             float* __restrict__ out) {
  const int l = threadIdx.x & 63, g = threadIdx.x >> 6;
  const float inv = 1.0f / (float)EDGES;
  const float mean = stats[l] * inv;
  const float ex2 = stats[64 + l] * inv;
  const float var = ex2 - mean * mean;
  const float a = gamma[l] * rsqrtf(var + 1e-5f);
  const float bb = fmaf(-mean, a, beta[l]);
  const float bl = bvec[l];
  const int base = blockIdx.x * NB_ST;
  for (int nn = g; nn < NB_ST; nn += 4) {
    const int node = base + nn;
    const float ui = u[(size_t)node * 64 + l] + bl;
    const int* ip = nidx + (size_t)node * K_NN;
    int idx[16];
    #pragma unroll
    for (int q = 0; q < 4; ++q)
      *(int4*)&idx[q * 4] = *(const int4*)(ip + q * 4);
    float acc = 0.f;
    #pragma unroll
    for (int k = 0; k < K_NN; ++k) {
      const float vj = v[(size_t)idx[k] * 64 + l];
      const float h = ui + vj;
      acc += fmaxf(fmaf(a, h, bb), 0.f);
    }
    out[(size_t)node * 64 + l] = acc * (1.0f / 16.0f);
  }
}

// ---------------- launcher ----------------
extern "C" void kernel_launch(void* const* d_in, const int* in_sizes, int n_in,
                              void* d_out, int out_size, void* d_ws, size_t ws_size,
                              hipStream_t stream) {
  (void)in_sizes; (void)n_in; (void)out_size;
  const float* x     = (const float*)d_in[0];
  const float* W     = (const float*)d_in[2];
  const float* b     = (const float*)d_in[3];
  const float* gamma = (const float*)d_in[4];
  const float* beta  = (const float*)d_in[5];
  float* out = (float*)d_out;

  char* ws = (char*)d_ws;
  float*          u     = (float*)(ws);                    //  8 MB
  float*          v     = (float*)(ws + 8388608);          //  8 MB
  float*          sq    = (float*)(ws + 16777216);         //  128 KB
  int*            nidx  = (int*)  (ws + 16908288);         //  2 MB
  float*          stats = (float*)(ws + 19005440);         //  512 B
  unsigned short* xh    = (unsigned short*)(ws + 19005952);//  4 MB
  unsigned short* xl    = (unsigned short*)(ws + 23200256);//  4 MB
  unsigned short* Sbuf  = (unsigned short*)(ws + 27394560);//  up to 134 MB

  const size_t sChunkBytes = (size_t)N_NODES * N_NODES * 2; // 8.4 MB per event
  size_t avail = (ws_size > 27394560) ? ws_size - 27394560 : 0;
  int evCap = (int)((avail / sChunkBytes < 16) ? (avail / sChunkBytes) : 16);

  hipMemsetAsync(stats, 0, 512, stream);
  k_uv  <<<512, 256, 0, stream>>>(x, W, u, v, sq, xh, xl);

  if (evCap >= 1) {
    for (int e0 = 0; e0 < B_EV; e0 += evCap) {
      int ne = (B_EV - e0 < evCap) ? (B_EV - e0) : evCap;
      k_gemm<<<ne * 128, 256, 0, stream>>>(xh, xl, sq, Sbuf, e0);
      k_sel <<<ne * 512, 256, 0, stream>>>(x, sq, Sbuf, nidx, e0 * N_NODES);
    }
  } else {
    k_knn<<<1024, 256, 0, stream>>>(x, xh, xl, sq, nidx);
  }

  k_stats<<<1024, 256, 0, stream>>>(u, v, nidx, b, stats);
  k_out <<<1024, 256, 0, stream>>>(u, v, nidx, b, gamma, beta, stats, out);
}

// Round 20
// 173.875 us; speedup vs baseline: 1.3135x; 1.3135x over previous
//
#include <hip/hip_runtime.h>
#include <hip/hip_fp16.h>
#include <math.h>

#define B_EV    16
#define N_NODES 2048
#define K_NN    16
#define F_IN    64
#define L_OUT   64
#define NT      (B_EV * N_NODES)      // 32768
#define EDGES   (NT * K_NN)           // 524288

typedef __attribute__((ext_vector_type(8)))  short bh8;    // 8 bf16 = 4 VGPR
typedef __attribute__((ext_vector_type(16))) float f32x16; // MFMA acc
typedef __attribute__((ext_vector_type(8)))  unsigned short us8;

__device__ inline unsigned short bf16_rne(float f) {
  unsigned int u = __float_as_uint(f);
  return (unsigned short)((u + 0x7FFFu + ((u >> 16) & 1u)) >> 16);
}
__device__ inline float bf16f(unsigned short h) {
  return __uint_as_float(((unsigned int)h) << 16);
}

// async global->LDS, 16B per lane; LDS dest must be wave-uniform base + lane*16
__device__ inline void gload16(const void* g, void* l) {
  __builtin_amdgcn_global_load_lds(
      (const __attribute__((address_space(1))) void*)(g),
      (__attribute__((address_space(3))) void*)(l), 16, 0, 0);
}

// exact numpy-fp32-emulated score -> monotone sortable 64-bit key (s32, idx)
__device__ inline unsigned long long score_key(const float* xiW,
                                               const float* __restrict__ xev,
                                               int mcol, float sqn,
                                               const float* __restrict__ sqev) {
  const float4* xm = (const float4*)(xev + (size_t)mcol * F_IN);
  double d0 = 0.0, d1 = 0.0, d2 = 0.0, d3 = 0.0;
  #pragma unroll
  for (int fq = 0; fq < 16; fq += 4) {
    float4 c0 = xm[fq + 0], c1 = xm[fq + 1], c2 = xm[fq + 2], c3 = xm[fq + 3];
    float4 x0 = *(const float4*)(xiW + fq * 4);
    float4 x1 = *(const float4*)(xiW + fq * 4 + 4);
    float4 x2 = *(const float4*)(xiW + fq * 4 + 8);
    float4 x3 = *(const float4*)(xiW + fq * 4 + 12);
    d0 = fma((double)x0.x, (double)c0.x, d0);
    d0 = fma((double)x0.y, (double)c0.y, d0);
    d0 = fma((double)x0.z, (double)c0.z, d0);
    d0 = fma((double)x0.w, (double)c0.w, d0);
    d1 = fma((double)x1.x, (double)c1.x, d1);
    d1 = fma((double)x1.y, (double)c1.y, d1);
    d1 = fma((double)x1.z, (double)c1.z, d1);
    d1 = fma((double)x1.w, (double)c1.w, d1);
    d2 = fma((double)x2.x, (double)c2.x, d2);
    d2 = fma((double)x2.y, (double)c2.y, d2);
    d2 = fma((double)x2.z, (double)c2.z, d2);
    d2 = fma((double)x2.w, (double)c2.w, d2);
    d3 = fma((double)x3.x, (double)c3.x, d3);
    d3 = fma((double)x3.y, (double)c3.y, d3);
    d3 = fma((double)x3.z, (double)c3.z, d3);
    d3 = fma((double)x3.w, (double)c3.w, d3);
  }
  float dot32 = (float)((d0 + d1) + (d2 + d3));
  float sv = __fsub_rn(__fadd_rn(sqn, sqev[mcol]), __fmul_rn(2.0f, dot32));
  unsigned int fb = __float_as_uint(sv);
  fb = (fb & 0x80000000u) ? ~fb : (fb | 0x80000000u);
  return ((unsigned long long)fb << 32) | (unsigned int)mcol;
}

// ---------------- K1: u = x@(W1-W2), v = x@W2  (+fused sq & bf16 hi/lo split) ----
__global__ __launch_bounds__(256) void k_uv(const float* __restrict__ x,
                                            const float* __restrict__ W,
                                            float* __restrict__ u,
                                            float* __restrict__ v,
                                            float* __restrict__ sq,
                                            unsigned short* __restrict__ xh,
                                            unsigned short* __restrict__ xl) {
  __shared__ float xs[64][64];   // 16 KB
  const int t = threadIdx.x;
  const int l = t & 63, g = t >> 6;
  const int nodeBase = blockIdx.x * 64;

  {
    const float4* gx = (const float4*)(x + (size_t)nodeBase * 64);
    float4* lx = (float4*)&xs[0][0];
    #pragma unroll
    for (int p = 0; p < 4; ++p) lx[p * 256 + t] = gx[p * 256 + t];
  }
  float wdc[64], w2c[64];
  #pragma unroll
  for (int f = 0; f < 64; ++f) {
    float w1v = W[f * 64 + l];
    float w2v = W[4096 + f * 64 + l];
    wdc[f] = w1v - w2v;
    w2c[f] = w2v;
  }
  __syncthreads();

  // fused sq: bit-exact numpy pairwise fp32 (8 lanes/node, shfl tree)
  #pragma unroll
  for (int p = 0; p < 2; ++p) {
    int n = p * 32 + (t >> 3), j = t & 7;
    float xv = xs[n][j];
    float s = __fmul_rn(xv, xv);
    #pragma unroll
    for (int i = 1; i < 8; ++i) {
      float c = xs[n][j + 8 * i];
      s = __fadd_rn(s, __fmul_rn(c, c));
    }
    s = __fadd_rn(s, __shfl_xor(s, 1));
    s = __fadd_rn(s, __shfl_xor(s, 2));
    s = __fadd_rn(s, __shfl_xor(s, 4));
    if (j == 0) sq[nodeBase + n] = s;
  }
  // fused cvt: 4 float4 per thread
  #pragma unroll
  for (int p = 0; p < 4; ++p) {
    int i = p * 256 + t;
    float4 vv = ((const float4*)&xs[0][0])[i];
    ushort4 h, lo;
    h.x = bf16_rne(vv.x); lo.x = bf16_rne(vv.x - bf16f(h.x));
    h.y = bf16_rne(vv.y); lo.y = bf16_rne(vv.y - bf16f(h.y));
    h.z = bf16_rne(vv.z); lo.z = bf16_rne(vv.z - bf16f(h.z));
    h.w = bf16_rne(vv.w); lo.w = bf16_rne(vv.w - bf16f(h.w));
    ((ushort4*)xh)[(size_t)nodeBase * 16 + i] = h;
    ((ushort4*)xl)[(size_t)nodeBase * 16 + i] = lo;
  }

  for (int rep = 0; rep < 16; ++rep) {
    int n = rep * 4 + g;
    const float4* xr = (const float4*)xs[n];
    float au = 0.f, av = 0.f;
    #pragma unroll
    for (int fq = 0; fq < 16; ++fq) {
      float4 xv = xr[fq];
      au = fmaf(xv.x, wdc[fq * 4 + 0], au); av = fmaf(xv.x, w2c[fq * 4 + 0], av);
      au = fmaf(xv.y, wdc[fq * 4 + 1], au); av = fmaf(xv.y, w2c[fq * 4 + 1], av);
      au = fmaf(xv.z, wdc[fq * 4 + 2], au); av = fmaf(xv.z, w2c[fq * 4 + 2], av);
      au = fmaf(xv.w, wdc[fq * 4 + 3], au); av = fmaf(xv.w, w2c[fq * 4 + 3], av);
    }
    u[(size_t)(nodeBase + n) * 64 + l] = au;
    v[(size_t)(nodeBase + n) * 64 + l] = av;
  }
}

// ---------------- K2a: strip GEMM -> S (fp16 screening, 2-pass MFMA, column-halved) ----------------
__global__ __launch_bounds__(256, 6) void k_gemm(const unsigned short* __restrict__ xh,
                                                 const unsigned short* __restrict__ xl,
                                                 const float* __restrict__ sq,
                                                 unsigned short* __restrict__ Sbuf,
                                                 int evBase) {
  __shared__ char xb[16384];                              // B-hi tile, swizzled
  __shared__ __align__(16) unsigned short Sh[32 * 128];   // fp16 S stage; prologue: A staging (8KB)
  const int t    = threadIdx.x;
  const int w    = t >> 6;
  const int lane = t & 63;
  const int ev    = evBase + (blockIdx.x >> 7);
  const int rem   = blockIdx.x & 127;
  const int strip = rem >> 1;
  const int half  = rem & 1;
  const int rowBase = strip * 32;
  const int T0 = half * 8;
  const size_t evNode = (size_t)ev * N_NODES;
  const float* __restrict__ sqev = sq + evNode;
  unsigned short* __restrict__ Sev =
      Sbuf + (size_t)(ev - evBase) * N_NODES * N_NODES;
  char* Sc = (char*)Sh;

  {
    int col = t >> 3;
    int fbs = ((t & 7) << 4) ^ ((col & 7) << 4);
    gload16((const char*)(xh + (evNode + rowBase + col) * 64) + fbs, Sc + t * 16);
    gload16((const char*)(xl + (evNode + rowBase + col) * 64) + fbs, Sc + 4096 + t * 16);
    #pragma unroll
    for (int p = 0; p < 4; ++p) {
      const int colB = p * 32 + (t >> 3);
      const char* g = (const char*)(xh + (evNode + T0 * 128 + colB) * 64) + fbs;
      gload16(g, xb + p * 4096 + t * 16);
    }
  }
  __syncthreads();
  bh8 ah[4], al[4];
  {
    int row = lane & 31;
    int fb  = (lane >> 5) * 16;
    #pragma unroll
    for (int ks = 0; ks < 4; ++ks) {
      int off = (row * 128 + ks * 32 + fb) ^ ((row & 7) << 4);
      ah[ks] = *(const bh8*)(Sc + off);
      al[ks] = *(const bh8*)(Sc + 4096 + off);
    }
  }
  __syncthreads();

  for (int T = T0; T < T0 + 8; ++T) {
    const int tileCol = T * 128;
    {
      f32x16 acc;
      #pragma unroll
      for (int q = 0; q < 16; ++q) acc[q] = 0.f;
      int colIn = w * 32 + (lane & 31);
      int fb = (lane >> 5) * 16;
      #pragma unroll
      for (int ks = 0; ks < 4; ++ks) {
        int off = (colIn * 128 + ks * 32 + fb) ^ ((colIn & 7) << 4);
        bh8 bh = *(const bh8*)(xb + off);
        acc = __builtin_amdgcn_mfma_f32_32x32x16_bf16(ah[ks], bh, acc, 0, 0, 0);
        acc = __builtin_amdgcn_mfma_f32_32x32x16_bf16(al[ks], bh, acc, 0, 0, 0);
      }
      float sqc = sqev[tileCol + colIn];
      #pragma unroll
      for (int reg = 0; reg < 16; ++reg) {
        int m = (reg & 3) + 8 * (reg >> 2) + 4 * (lane >> 5);
        Sh[m * 128 + colIn] =
            __half_as_ushort(__float2half(fmaf(-2.0f, acc[reg], sqc)));
      }
    }
    __syncthreads();
    if (T < T0 + 7) {
      #pragma unroll
      for (int p = 0; p < 4; ++p) {
        const int colB = p * 32 + (t >> 3);
        const int fbs = ((t & 7) << 4) ^ (((t >> 3) & 7) << 4);
        const char* g = (const char*)(xh + (evNode + tileCol + 128 + colB) * 64) + fbs;
        gload16(g, xb + p * 4096 + t * 16);
      }
    }
    {
      int r  = t >> 3;
      int cg = t & 7;
      unsigned short* gS =
          Sev + (size_t)(rowBase + r) * N_NODES + tileCol + cg * 16;
      const uint4* lS = (const uint4*)(Sh + r * 128 + cg * 16);
      *(uint4*)gS = lS[0];
      *(uint4*)(gS + 8) = lS[1];
    }
    __syncthreads();
  }
}

// ---------------- K2b: fused screening + exact rescore + rank top-16 (per-wave) ----------------
// Round-16 validated version: exact-16th bitonic threshold (minimizes survivor
// count, which drives rescore+rank cost), single row per wave.
#define SCR_CAP 192
#define SEL_DELTA 1.0f

__global__ __launch_bounds__(256, 1) void k_sel(const float* __restrict__ x,
                                                const float* __restrict__ sq,
                                                const unsigned short* __restrict__ Sbuf,
                                                int* __restrict__ nidx,
                                                int rowBase) {
  __shared__ float xiS[4][64];
  __shared__ int candLDS[4][SCR_CAP];
  __shared__ unsigned long long keysLDS[4][SCR_CAP];
  const int w = threadIdx.x >> 6, lane = threadIdx.x & 63;
  const int rowInChunk = blockIdx.x * 4 + w;
  const int grow = rowBase + rowInChunk;
  const int ev = grow >> 11;
  const int rowInEv = grow & 2047;
  const size_t evNode = (size_t)ev * N_NODES;
  const unsigned short* __restrict__ Srow = Sbuf + (size_t)rowInChunk * N_NODES;
  const float* __restrict__ sqev = sq + evNode;
  const float* __restrict__ xev = x + evNode * F_IN;

  xiS[w][lane] = x[(evNode + rowInEv) * F_IN + lane];   // per-wave slice; no barrier needed

  // ---- screening: load 4x us8, lane-min, bitonic, thr ----
  us8 pk[4];
  #pragma unroll
  for (int q = 0; q < 4; ++q)
    pk[q] = *(const us8*)(Srow + q * 512 + lane * 8);

  float mn = 3.4e38f;
  #pragma unroll
  for (int q = 0; q < 4; ++q) {
    #pragma unroll
    for (int e = 0; e < 8; ++e)
      mn = fminf(mn, __half2float(__ushort_as_half(pk[q][e])));
  }
  #pragma unroll
  for (int k = 2; k <= 64; k <<= 1) {
    #pragma unroll
    for (int j = k >> 1; j >= 1; j >>= 1) {
      float o = __shfl_xor(mn, j);
      bool up = ((lane & k) == 0);
      bool iAmLower = ((lane & j) == 0);
      bool wantSmall = (up == iAmLower);
      bool less = (mn < o);
      if (less != wantSmall) mn = o;
    }
  }
  const float thr = __shfl(mn, 15) + SEL_DELTA;

  // ---- ballot-free compact via prefix scan into LDS ----
  unsigned int msk[4];
  int c = 0;
  #pragma unroll
  for (int q = 0; q < 4; ++q) {
    unsigned int m = 0;
    #pragma unroll
    for (int e = 0; e < 8; ++e) {
      float v = __half2float(__ushort_as_half(pk[q][e]));
      m |= (v <= thr) ? (1u << e) : 0u;
    }
    msk[q] = m;
    c += __popc(m);
  }
  int incl = c;
  #pragma unroll
  for (int off = 1; off < 64; off <<= 1) {
    int n = __shfl_up(incl, off);
    if (lane >= off) incl += n;
  }
  int pos = incl - c;
  int total = __shfl(incl, 63);
  const int cn = (total < SCR_CAP) ? total : SCR_CAP;
  #pragma unroll
  for (int q = 0; q < 4; ++q) {
    unsigned int m = msk[q];
    while (m) {
      int e = __ffs(m) - 1;
      m &= m - 1;
      if (pos < SCR_CAP) candLDS[w][pos] = q * 512 + lane * 8 + e;
      ++pos;
    }
  }

  // ---- exact rescore (numpy-fp32-emulated; fp64 dot) ----
  const float sqn = sqev[rowInEv];
  const float* xiW = xiS[w];
  const int* crow = candLDS[w];

  int base = 0;
  while (base < cn) {
    int rem = cn - base;
    if (rem <= 32) {
      int hf = lane >> 5;
      int ii = lane & 31;
      int ci = base + ii;
      bool act = ii < rem;
      int mcol = act ? crow[ci] : 0;
      const float4* xm = (const float4*)(xev + (size_t)mcol * F_IN);
      double d0 = 0.0, d1 = 0.0;
      #pragma unroll
      for (int q = 0; q < 8; ++q) {
        int fq = hf * 8 + q;
        float4 cc = xm[fq];
        float4 xq = *(const float4*)(xiW + fq * 4);
        d0 = fma((double)xq.x, (double)cc.x, d0);
        d1 = fma((double)xq.y, (double)cc.y, d1);
        d0 = fma((double)xq.z, (double)cc.z, d0);
        d1 = fma((double)xq.w, (double)cc.w, d1);
      }
      double ds = d0 + d1;
      double od = __shfl_xor(ds, 32);
      if (act && hf == 0) {
        float dot32 = (float)(ds + od);
        float sv = __fsub_rn(__fadd_rn(sqn, sqev[mcol]), __fmul_rn(2.0f, dot32));
        unsigned int fb = __float_as_uint(sv);
        fb = (fb & 0x80000000u) ? ~fb : (fb | 0x80000000u);
        keysLDS[w][ci] = ((unsigned long long)fb << 32) | (unsigned int)mcol;
      }
      base = cn;
    } else {
      int ci = base + lane;
      bool act = ci < cn;
      int mcol = act ? crow[ci] : 0;
      unsigned long long key = score_key(xiW, xev, mcol, sqn, sqev);
      if (act) keysLDS[w][ci] = key;
      base += 64;
    }
  }

  // ---- rank via single broadcast pass (keys unique; stable ties by idx) ----
  const unsigned long long INVALID = ~0ull;
  unsigned long long k0 = INVALID, k1 = INVALID, k2 = INVALID;
  if (lane < cn)        k0 = keysLDS[w][lane];
  if (lane + 64 < cn)   k1 = keysLDS[w][lane + 64];
  if (lane + 128 < cn)  k2 = keysLDS[w][lane + 128];
  int r0 = 0, r1 = 0, r2 = 0;
  for (int i = 0; i < cn; ++i) {
    unsigned long long kk = keysLDS[w][i];
    r0 += (kk < k0) ? 1 : 0;
    r1 += (kk < k1) ? 1 : 0;
    r2 += (kk < k2) ? 1 : 0;
  }
  const size_t outBase = (evNode + rowInEv) * K_NN;
  if (lane < cn && r0 < K_NN)
    nidx[outBase + r0] = (int)evNode + (int)(k0 & 0x7FFFFFFFu);
  if (lane + 64 < cn && r1 < K_NN)
    nidx[outBase + r1] = (int)evNode + (int)(k1 & 0x7FFFFFFFu);
  if (lane + 128 < cn && r2 < K_NN)
    nidx[outBase + r2] = (int)evNode + (int)(k2 & 0x7FFFFFFFu);
}

// ---------------- K3: BN statistics over all edges ----------------
#define NB_ST 32
__global__ __launch_bounds__(256) void k_stats(const float* __restrict__ u,
                                               const float* __restrict__ v,
                                               const int* __restrict__ nidx,
                                               const float* __restrict__ bvec,
                                               float* __restrict__ stats) {
  __shared__ float red1[4][64];
  __shared__ float red2[4][64];
  const int l = threadIdx.x & 63, g = threadIdx.x >> 6;
  const int base = blockIdx.x * NB_ST;
  const float bl = bvec[l];
  float s1 = 0.f, s2 = 0.f;
  for (int nn = g; nn < NB_ST; nn += 4) {
    const int node = base + nn;
    const float ui = u[(size_t)node * 64 + l] + bl;
    const int* ip = nidx + (size_t)node * K_NN;
    int idx[16];
    #pragma unroll
    for (int q = 0; q < 4; ++q)
      *(int4*)&idx[q * 4] = *(const int4*)(ip + q * 4);
    #pragma unroll
    for (int k = 0; k < K_NN; ++k) {
      const float vj = v[(size_t)idx[k] * 64 + l];
      const float h = ui + vj;
      s1 += h;
      s2 = fmaf(h, h, s2);
    }
  }
  red1[g][l] = s1; red2[g][l] = s2;
  __syncthreads();
  if (g == 0) {
    float t1 = red1[0][l] + red1[1][l] + red1[2][l] + red1[3][l];
    float t2 = red2[0][l] + red2[1][l] + red2[2][l] + red2[3][l];
    atomicAdd(&stats[l], t1);
    atomicAdd(&stats[64 + l], t2);
  }
}

// ---------------- K4: normalize + relu + mean over K ----------------
__global__ __launch_bounds__(256) void k_out(const float* __restrict__ u,
                                             const float* __restrict__ v,
                                             const int* __restrict__ nidx,
                                             const float* __restrict__ bvec,
                                             const float* __restrict__ gamma,
                                             const float* __restrict__ beta,
                                             const float* __restrict__ stats,
                                             float* __restrict__ out) {
  const int l = threadIdx.x & 63, g = threadIdx.x >> 6;
  const float inv = 1.0f / (float)EDGES;
  const float mean = stats[l] * inv;
  const float ex2 = stats[64 + l] * inv;
  const float var = ex2 - mean * mean;
  const float a = gamma[l] * rsqrtf(var + 1e-5f);
  const float bb = fmaf(-mean, a, beta[l]);
  const float bl = bvec[l];
  const int base = blockIdx.x * NB_ST;
  for (int nn = g; nn < NB_ST; nn += 4) {
    const int node = base + nn;
    const float ui = u[(size_t)node * 64 + l] + bl;
    const int* ip = nidx + (size_t)node * K_NN;
    int idx[16];
    #pragma unroll
    for (int q = 0; q < 4; ++q)
      *(int4*)&idx[q * 4] = *(const int4*)(ip + q * 4);
    float acc = 0.f;
    #pragma unroll
    for (int k = 0; k < K_NN; ++k) {
      const float vj = v[(size_t)idx[k] * 64 + l];
      const float h = ui + vj;
      acc += fmaxf(fmaf(a, h, bb), 0.f);
    }
    out[(size_t)node * 64 + l] = acc * (1.0f / 16.0f);
  }
}

// ---------------- launcher ----------------
extern "C" void kernel_launch(void* const* d_in, const int* in_sizes, int n_in,
                              void* d_out, int out_size, void* d_ws, size_t ws_size,
                              hipStream_t stream) {
  (void)in_sizes; (void)n_in; (void)out_size;
  const float* x     = (const float*)d_in[0];
  const float* W     = (const float*)d_in[2];
  const float* b     = (const float*)d_in[3];
  const float* gamma = (const float*)d_in[4];
  const float* beta  = (const float*)d_in[5];
  float* out = (float*)d_out;

  char* ws = (char*)d_ws;
  float*          u     = (float*)(ws);                    //  8 MB
  float*          v     = (float*)(ws + 8388608);          //  8 MB
  float*          sq    = (float*)(ws + 16777216);         //  128 KB
  int*            nidx  = (int*)  (ws + 16908288);         //  2 MB
  float*          stats = (float*)(ws + 19005440);         //  512 B
  unsigned short* xh    = (unsigned short*)(ws + 19005952);//  4 MB
  unsigned short* xl    = (unsigned short*)(ws + 23200256);//  4 MB
  unsigned short* Sbuf  = (unsigned short*)(ws + 27394560);//  up to 134 MB

  const size_t sChunkBytes = (size_t)N_NODES * N_NODES * 2; // 8.4 MB per event
  size_t avail = (ws_size > 27394560) ? ws_size - 27394560 : 0;
  int evCap = (int)((avail / sChunkBytes < 16) ? (avail / sChunkBytes) : 16);
  if (evCap < 1) evCap = 1;   // Sbuf region is sized in the harness workspace

  hipMemsetAsync(stats, 0, 512, stream);
  k_uv  <<<512, 256, 0, stream>>>(x, W, u, v, sq, xh, xl);

  for (int e0 = 0; e0 < B_EV; e0 += evCap) {
    int ne = (B_EV - e0 < evCap) ? (B_EV - e0) : evCap;
    k_gemm<<<ne * 128, 256, 0, stream>>>(xh, xl, sq, Sbuf, e0);
    k_sel <<<ne * 512, 256, 0, stream>>>(x, sq, Sbuf, nidx, e0 * N_NODES);
  }

  k_stats<<<1024, 256, 0, stream>>>(u, v, nidx, b, stats);
  k_out <<<1024, 256, 0, stream>>>(u, v, nidx, b, gamma, beta, stats, out);
}